// Round 1
// baseline (4675.443 us; speedup 1.0000x reference)
//
#include <hip/hip_runtime.h>
#include <cstdint>
#include <cstddef>

#define TT 20
#define BB 262144

// f64 weight scratch layout (element offsets, in doubles):
//   W1T [10][64] @ 0       (W1T[k][o] = W1[o][k])
//   W2T [64][32] @ 640
//   W3T [32][32] @ 2688
//   W4T [32][16] @ 3712
//   W5T [16][6]  @ 4224    total 4320 doubles = 34560 B
#define OFF_W2T 640
#define OFF_W3T 2688
#define OFF_W4T 3712
#define OFF_W5T 4224
#define W_TOTAL 4320

__global__ void prep_weights(const float* __restrict__ W1, const float* __restrict__ W2,
                             const float* __restrict__ W3, const float* __restrict__ W4,
                             const float* __restrict__ W5, double* __restrict__ Wd) {
  int stride = blockDim.x * gridDim.x;
  for (int idx = blockIdx.x * blockDim.x + threadIdx.x; idx < W_TOTAL; idx += stride) {
    double v;
    if (idx < OFF_W2T) {
      int j = idx;            int k = j / 64, o = j % 64; v = (double)W1[o * 10 + k];
    } else if (idx < OFF_W3T) {
      int j = idx - OFF_W2T;  int k = j / 32, o = j % 32; v = (double)W2[o * 64 + k];
    } else if (idx < OFF_W4T) {
      int j = idx - OFF_W3T;  int k = j / 32, o = j % 32; v = (double)W3[o * 32 + k];
    } else if (idx < OFF_W5T) {
      int j = idx - OFF_W4T;  int k = j / 16, o = j % 16; v = (double)W4[o * 32 + k];
    } else {
      int j = idx - OFF_W5T;  int k = j / 6,  o = j % 6;  v = (double)W5[o * 16 + k];
    }
    Wd[idx] = v;
  }
}

// One thread = one batch element. All membrane state in registers (f64).
// ~300 VGPRs of persistent state -> launch_bounds(256,1) to allow up to 512.
__global__ __launch_bounds__(256, 1) void snn_f64(const float* __restrict__ x,
                                                  const double* __restrict__ Wd,
                                                  float* __restrict__ out) {
  const int e = blockIdx.x * blockDim.x + threadIdx.x;

  const double* __restrict__ W1T = Wd;
  const double* __restrict__ W2T = Wd + OFF_W2T;
  const double* __restrict__ W3T = Wd + OFF_W3T;
  const double* __restrict__ W4T = Wd + OFF_W4T;
  const double* __restrict__ W5T = Wd + OFF_W5T;

  double m1[64], m2[32], m3[32], m4[16], m5[6];
#pragma unroll
  for (int o = 0; o < 64; ++o) m1[o] = 0.0;
#pragma unroll
  for (int o = 0; o < 32; ++o) m2[o] = 0.0;
#pragma unroll
  for (int o = 0; o < 32; ++o) m3[o] = 0.0;
#pragma unroll
  for (int o = 0; o < 16; ++o) m4[o] = 0.0;
#pragma unroll
  for (int o = 0; o < 6; ++o) m5[o] = 0.0;

#pragma unroll 1
  for (int t = 0; t < TT; ++t) {
    // ---- load x[t][e][0..9] (40 B, 8-aligned) ----
    const float* xp = x + ((size_t)t * BB + e) * 10;
    float xv[10];
#pragma unroll
    for (int i = 0; i < 5; ++i) {
      float2 f = ((const float2*)xp)[i];
      xv[2 * i] = f.x; xv[2 * i + 1] = f.y;
    }

    // ================= Layer 1 (10 -> 64) =================
    // reset on incoming mem, pre-scale, then accumulate current.
#pragma unroll
    for (int o = 0; o < 64; ++o) {
      double sub = (m1[o] > 1.0) ? 1.0 : 0.0;
      m1[o] = 0.9 * m1[o] - sub;
    }
#pragma unroll
    for (int k = 0; k < 10; ++k) {
      double s = (double)xv[k];
      const double* col = W1T + k * 64;
#pragma unroll
      for (int o = 0; o < 64; ++o) m1[o] = fma(s, col[o], m1[o]);
    }
    unsigned long long msk1 = 0ull;
#pragma unroll
    for (int o = 0; o < 64; ++o) msk1 |= (m1[o] > 1.0) ? (1ull << o) : 0ull;

    // ================= Layer 2 (64 -> 32) =================
#pragma unroll
    for (int o = 0; o < 32; ++o) {
      double sub = (m2[o] > 1.0) ? 1.0 : 0.0;
      m2[o] = 0.9 * m2[o] - sub;
    }
    {
      unsigned long long m = msk1;
      const double* col = W2T;
      for (int k = 0; k < 64; ++k) {
        double s = (double)(unsigned int)(m & 1ull);
        m >>= 1;
#pragma unroll
        for (int o = 0; o < 32; ++o) m2[o] = fma(s, col[o], m2[o]);
        col += 32;
      }
    }
    unsigned int msk2 = 0u;
#pragma unroll
    for (int o = 0; o < 32; ++o) msk2 |= (m2[o] > 1.0) ? (1u << o) : 0u;

    // ================= Layer 3 (32 -> 32) =================
#pragma unroll
    for (int o = 0; o < 32; ++o) {
      double sub = (m3[o] > 1.0) ? 1.0 : 0.0;
      m3[o] = 0.9 * m3[o] - sub;
    }
    {
      unsigned int m = msk2;
      const double* col = W3T;
      for (int k = 0; k < 32; ++k) {
        double s = (double)(m & 1u);
        m >>= 1;
#pragma unroll
        for (int o = 0; o < 32; ++o) m3[o] = fma(s, col[o], m3[o]);
        col += 32;
      }
    }
    unsigned int msk3 = 0u;
#pragma unroll
    for (int o = 0; o < 32; ++o) msk3 |= (m3[o] > 1.0) ? (1u << o) : 0u;

    // ================= Layer 4 (32 -> 16) =================
#pragma unroll
    for (int o = 0; o < 16; ++o) {
      double sub = (m4[o] > 1.0) ? 1.0 : 0.0;
      m4[o] = 0.9 * m4[o] - sub;
    }
    {
      unsigned int m = msk3;
      const double* col = W4T;
      for (int k = 0; k < 32; ++k) {
        double s = (double)(m & 1u);
        m >>= 1;
#pragma unroll
        for (int o = 0; o < 16; ++o) m4[o] = fma(s, col[o], m4[o]);
        col += 16;
      }
    }
    unsigned int msk4 = 0u;
#pragma unroll
    for (int o = 0; o < 16; ++o) msk4 |= (m4[o] > 1.0) ? (1u << o) : 0u;

    // ================= Layer 5 (16 -> 6) =================
#pragma unroll
    for (int o = 0; o < 6; ++o) {
      double sub = (m5[o] > 1.0) ? 1.0 : 0.0;
      m5[o] = 0.9 * m5[o] - sub;
    }
    {
      unsigned int m = msk4;
      const double* col = W5T;
      for (int k = 0; k < 16; ++k) {
        double s = (double)(m & 1u);
        m >>= 1;
#pragma unroll
        for (int o = 0; o < 6; ++o) m5[o] = fma(s, col[o], m5[o]);
        col += 6;
      }
    }

    // ---- output spikes: out[t][e][0..5], binary f32 ----
    float ov[6];
#pragma unroll
    for (int o = 0; o < 6; ++o) ov[o] = (m5[o] > 1.0) ? 1.0f : 0.0f;
    float* op = out + ((size_t)t * BB + e) * 6;
    ((float2*)op)[0] = make_float2(ov[0], ov[1]);
    ((float2*)op)[1] = make_float2(ov[2], ov[3]);
    ((float2*)op)[2] = make_float2(ov[4], ov[5]);
  }
}

extern "C" void kernel_launch(void* const* d_in, const int* in_sizes, int n_in,
                              void* d_out, int out_size, void* d_ws, size_t ws_size,
                              hipStream_t stream) {
  const float* x  = (const float*)d_in[0];
  const float* W1 = (const float*)d_in[1];
  const float* W2 = (const float*)d_in[2];
  const float* W3 = (const float*)d_in[3];
  const float* W4 = (const float*)d_in[4];
  const float* W5 = (const float*)d_in[5];
  float* out = (float*)d_out;
  double* Wd = (double*)d_ws;   // 34560 B of f64 weights

  prep_weights<<<17, 256, 0, stream>>>(W1, W2, W3, W4, W5, Wd);
  snn_f64<<<BB / 256, 256, 0, stream>>>(x, Wd, out);
}

// Round 2
// 1541.300 us; speedup vs baseline: 3.0334x; 3.0334x over previous
//
#include <hip/hip_runtime.h>
#include <cstdint>
#include <cstddef>

#define TT 20
#define BB 262144

// f64 weight scratch layout (element offsets, in doubles):
//   W1T [10][64] @ 0       (W1T[k][o] = W1[o][k])
//   W2T [64][32] @ 640
//   W3T [32][32] @ 2688
//   W4T [32][16] @ 3712
//   W5T [16][6]  @ 4224    total 4320 doubles = 34560 B
#define OFF_W2T 640
#define OFF_W3T 2688
#define OFF_W4T 3712
#define OFF_W5T 4224
#define W_TOTAL 4320

// workspace layout (bytes)
#define WS_WD_BYTES 34560
#define WS_MASK_BASE 34816                      // 256-aligned
#define WS_MASK_STRIDE (TT * BB * 4)            // 20.97 MB per uint32 mask plane
#define WS_NEEDED (WS_MASK_BASE + 3 * (size_t)WS_MASK_STRIDE)

__global__ void prep_weights(const float* __restrict__ W1, const float* __restrict__ W2,
                             const float* __restrict__ W3, const float* __restrict__ W4,
                             const float* __restrict__ W5, double* __restrict__ Wd) {
  int stride = blockDim.x * gridDim.x;
  for (int idx = blockIdx.x * blockDim.x + threadIdx.x; idx < W_TOTAL; idx += stride) {
    double v;
    if (idx < OFF_W2T) {
      int j = idx;            int k = j / 64, o = j % 64; v = (double)W1[o * 10 + k];
    } else if (idx < OFF_W3T) {
      int j = idx - OFF_W2T;  int k = j / 32, o = j % 32; v = (double)W2[o * 64 + k];
    } else if (idx < OFF_W4T) {
      int j = idx - OFF_W3T;  int k = j / 32, o = j % 32; v = (double)W3[o * 32 + k];
    } else if (idx < OFF_W5T) {
      int j = idx - OFF_W4T;  int k = j / 16, o = j % 16; v = (double)W4[o * 32 + k];
    } else {
      int j = idx - OFF_W5T;  int k = j / 6,  o = j % 6;  v = (double)W5[o * 16 + k];
    }
    Wd[idx] = v;
  }
}

// ---------------- split path: layer-group kernels, masks via d_ws ----------------

// Layer 1 (10 -> 64), split: each thread owns 32 neurons (half h).
// grid = 2048 blocks of 256: blockIdx.x < 1024 -> h=0 (neurons 0..31, lo mask),
// else h=1 (neurons 32..63, hi mask).
__global__ __launch_bounds__(256, 4) void snn_l1(const float* __restrict__ x,
                                                 const double* __restrict__ Wd,
                                                 uint32_t* __restrict__ mlo,
                                                 uint32_t* __restrict__ mhi) {
  const int h = (blockIdx.x >= 1024) ? 1 : 0;
  const int e = ((blockIdx.x & 1023) * 256) + threadIdx.x;
  const double* __restrict__ W1T = Wd + h * 32;   // columns for this half
  uint32_t* __restrict__ dst = h ? mhi : mlo;

  double m[32];
#pragma unroll
  for (int o = 0; o < 32; ++o) m[o] = 0.0;

#pragma unroll 1
  for (int t = 0; t < TT; ++t) {
    const float* xp = x + ((size_t)t * BB + e) * 10;
    float xv[10];
#pragma unroll
    for (int i = 0; i < 5; ++i) {
      float2 f = ((const float2*)xp)[i];
      xv[2 * i] = f.x; xv[2 * i + 1] = f.y;
    }
#pragma unroll
    for (int o = 0; o < 32; ++o) {
      double sub = (m[o] > 1.0) ? 1.0 : 0.0;
      m[o] = 0.9 * m[o] - sub;
    }
#pragma unroll
    for (int k = 0; k < 10; ++k) {
      double s = (double)xv[k];
      const double* col = W1T + k * 64;
#pragma unroll
      for (int o = 0; o < 32; ++o) m[o] = fma(s, col[o], m[o]);
    }
    uint32_t msk = 0u;
#pragma unroll
    for (int o = 0; o < 32; ++o) msk |= (m[o] > 1.0) ? (1u << o) : 0u;
    dst[(size_t)t * BB + e] = msk;
  }
}

// Layer 2 (64 -> 32): reads mlo/mhi, writes m2 mask.
__global__ __launch_bounds__(256, 4) void snn_l2(const double* __restrict__ Wd,
                                                 const uint32_t* __restrict__ mlo,
                                                 const uint32_t* __restrict__ mhi,
                                                 uint32_t* __restrict__ m2out) {
  const int e = blockIdx.x * 256 + threadIdx.x;
  const double* __restrict__ W2T = Wd + OFF_W2T;

  double m[32];
#pragma unroll
  for (int o = 0; o < 32; ++o) m[o] = 0.0;

#pragma unroll 1
  for (int t = 0; t < TT; ++t) {
    uint32_t blo = mlo[(size_t)t * BB + e];
    uint32_t bhi = mhi[(size_t)t * BB + e];
#pragma unroll
    for (int o = 0; o < 32; ++o) {
      double sub = (m[o] > 1.0) ? 1.0 : 0.0;
      m[o] = 0.9 * m[o] - sub;
    }
    {
      const double* col = W2T;
      uint32_t b = blo;
      for (int k = 0; k < 32; ++k) {
        double s = (double)(b & 1u);
        b >>= 1;
#pragma unroll
        for (int o = 0; o < 32; ++o) m[o] = fma(s, col[o], m[o]);
        col += 32;
      }
      b = bhi;
      for (int k = 0; k < 32; ++k) {
        double s = (double)(b & 1u);
        b >>= 1;
#pragma unroll
        for (int o = 0; o < 32; ++o) m[o] = fma(s, col[o], m[o]);
        col += 32;
      }
    }
    uint32_t msk = 0u;
#pragma unroll
    for (int o = 0; o < 32; ++o) msk |= (m[o] > 1.0) ? (1u << o) : 0u;
    m2out[(size_t)t * BB + e] = msk;
  }
}

// Layers 3+4+5 fused (32 -> 32 -> 16 -> 6): reads m2 mask, writes final spikes.
__global__ __launch_bounds__(256, 3) void snn_l345(const double* __restrict__ Wd,
                                                   const uint32_t* __restrict__ m2in,
                                                   float* __restrict__ out) {
  const int e = blockIdx.x * 256 + threadIdx.x;
  const double* __restrict__ W3T = Wd + OFF_W3T;
  const double* __restrict__ W4T = Wd + OFF_W4T;
  const double* __restrict__ W5T = Wd + OFF_W5T;

  double m3[32], m4[16], m5[6];
#pragma unroll
  for (int o = 0; o < 32; ++o) m3[o] = 0.0;
#pragma unroll
  for (int o = 0; o < 16; ++o) m4[o] = 0.0;
#pragma unroll
  for (int o = 0; o < 6; ++o) m5[o] = 0.0;

#pragma unroll 1
  for (int t = 0; t < TT; ++t) {
    uint32_t msk2 = m2in[(size_t)t * BB + e];

    // layer 3
#pragma unroll
    for (int o = 0; o < 32; ++o) {
      double sub = (m3[o] > 1.0) ? 1.0 : 0.0;
      m3[o] = 0.9 * m3[o] - sub;
    }
    {
      uint32_t b = msk2;
      const double* col = W3T;
      for (int k = 0; k < 32; ++k) {
        double s = (double)(b & 1u);
        b >>= 1;
#pragma unroll
        for (int o = 0; o < 32; ++o) m3[o] = fma(s, col[o], m3[o]);
        col += 32;
      }
    }
    uint32_t msk3 = 0u;
#pragma unroll
    for (int o = 0; o < 32; ++o) msk3 |= (m3[o] > 1.0) ? (1u << o) : 0u;

    // layer 4
#pragma unroll
    for (int o = 0; o < 16; ++o) {
      double sub = (m4[o] > 1.0) ? 1.0 : 0.0;
      m4[o] = 0.9 * m4[o] - sub;
    }
    {
      uint32_t b = msk3;
      const double* col = W4T;
      for (int k = 0; k < 32; ++k) {
        double s = (double)(b & 1u);
        b >>= 1;
#pragma unroll
        for (int o = 0; o < 16; ++o) m4[o] = fma(s, col[o], m4[o]);
        col += 16;
      }
    }
    uint32_t msk4 = 0u;
#pragma unroll
    for (int o = 0; o < 16; ++o) msk4 |= (m4[o] > 1.0) ? (1u << o) : 0u;

    // layer 5
#pragma unroll
    for (int o = 0; o < 6; ++o) {
      double sub = (m5[o] > 1.0) ? 1.0 : 0.0;
      m5[o] = 0.9 * m5[o] - sub;
    }
    {
      uint32_t b = msk4;
      const double* col = W5T;
      for (int k = 0; k < 16; ++k) {
        double s = (double)(b & 1u);
        b >>= 1;
#pragma unroll
        for (int o = 0; o < 6; ++o) m5[o] = fma(s, col[o], m5[o]);
        col += 6;
      }
    }

    float ov[6];
#pragma unroll
    for (int o = 0; o < 6; ++o) ov[o] = (m5[o] > 1.0) ? 1.0f : 0.0f;
    float* op = out + ((size_t)t * BB + e) * 6;
    ((float2*)op)[0] = make_float2(ov[0], ov[1]);
    ((float2*)op)[1] = make_float2(ov[2], ov[3]);
    ((float2*)op)[2] = make_float2(ov[4], ov[5]);
  }
}

// ---------------- fallback: round-1 monolithic kernel (ws too small) ----------------

__global__ __launch_bounds__(256, 1) void snn_f64(const float* __restrict__ x,
                                                  const double* __restrict__ Wd,
                                                  float* __restrict__ out) {
  const int e = blockIdx.x * blockDim.x + threadIdx.x;
  const double* __restrict__ W1T = Wd;
  const double* __restrict__ W2T = Wd + OFF_W2T;
  const double* __restrict__ W3T = Wd + OFF_W3T;
  const double* __restrict__ W4T = Wd + OFF_W4T;
  const double* __restrict__ W5T = Wd + OFF_W5T;

  double m1[64], m2[32], m3[32], m4[16], m5[6];
#pragma unroll
  for (int o = 0; o < 64; ++o) m1[o] = 0.0;
#pragma unroll
  for (int o = 0; o < 32; ++o) m2[o] = 0.0;
#pragma unroll
  for (int o = 0; o < 32; ++o) m3[o] = 0.0;
#pragma unroll
  for (int o = 0; o < 16; ++o) m4[o] = 0.0;
#pragma unroll
  for (int o = 0; o < 6; ++o) m5[o] = 0.0;

#pragma unroll 1
  for (int t = 0; t < TT; ++t) {
    const float* xp = x + ((size_t)t * BB + e) * 10;
    float xv[10];
#pragma unroll
    for (int i = 0; i < 5; ++i) {
      float2 f = ((const float2*)xp)[i];
      xv[2 * i] = f.x; xv[2 * i + 1] = f.y;
    }
#pragma unroll
    for (int o = 0; o < 64; ++o) {
      double sub = (m1[o] > 1.0) ? 1.0 : 0.0;
      m1[o] = 0.9 * m1[o] - sub;
    }
#pragma unroll
    for (int k = 0; k < 10; ++k) {
      double s = (double)xv[k];
      const double* col = W1T + k * 64;
#pragma unroll
      for (int o = 0; o < 64; ++o) m1[o] = fma(s, col[o], m1[o]);
    }
    unsigned long long msk1 = 0ull;
#pragma unroll
    for (int o = 0; o < 64; ++o) msk1 |= (m1[o] > 1.0) ? (1ull << o) : 0ull;

#pragma unroll
    for (int o = 0; o < 32; ++o) {
      double sub = (m2[o] > 1.0) ? 1.0 : 0.0;
      m2[o] = 0.9 * m2[o] - sub;
    }
    {
      unsigned long long m = msk1;
      const double* col = W2T;
      for (int k = 0; k < 64; ++k) {
        double s = (double)(unsigned int)(m & 1ull);
        m >>= 1;
#pragma unroll
        for (int o = 0; o < 32; ++o) m2[o] = fma(s, col[o], m2[o]);
        col += 32;
      }
    }
    unsigned int msk2 = 0u;
#pragma unroll
    for (int o = 0; o < 32; ++o) msk2 |= (m2[o] > 1.0) ? (1u << o) : 0u;

#pragma unroll
    for (int o = 0; o < 32; ++o) {
      double sub = (m3[o] > 1.0) ? 1.0 : 0.0;
      m3[o] = 0.9 * m3[o] - sub;
    }
    {
      unsigned int m = msk2;
      const double* col = W3T;
      for (int k = 0; k < 32; ++k) {
        double s = (double)(m & 1u);
        m >>= 1;
#pragma unroll
        for (int o = 0; o < 32; ++o) m3[o] = fma(s, col[o], m3[o]);
        col += 32;
      }
    }
    unsigned int msk3 = 0u;
#pragma unroll
    for (int o = 0; o < 32; ++o) msk3 |= (m3[o] > 1.0) ? (1u << o) : 0u;

#pragma unroll
    for (int o = 0; o < 16; ++o) {
      double sub = (m4[o] > 1.0) ? 1.0 : 0.0;
      m4[o] = 0.9 * m4[o] - sub;
    }
    {
      unsigned int m = msk3;
      const double* col = W4T;
      for (int k = 0; k < 32; ++k) {
        double s = (double)(m & 1u);
        m >>= 1;
#pragma unroll
        for (int o = 0; o < 16; ++o) m4[o] = fma(s, col[o], m4[o]);
        col += 16;
      }
    }
    unsigned int msk4 = 0u;
#pragma unroll
    for (int o = 0; o < 16; ++o) msk4 |= (m4[o] > 1.0) ? (1u << o) : 0u;

#pragma unroll
    for (int o = 0; o < 6; ++o) {
      double sub = (m5[o] > 1.0) ? 1.0 : 0.0;
      m5[o] = 0.9 * m5[o] - sub;
    }
    {
      unsigned int m = msk4;
      const double* col = W5T;
      for (int k = 0; k < 16; ++k) {
        double s = (double)(m & 1u);
        m >>= 1;
#pragma unroll
        for (int o = 0; o < 6; ++o) m5[o] = fma(s, col[o], m5[o]);
        col += 6;
      }
    }

    float ov[6];
#pragma unroll
    for (int o = 0; o < 6; ++o) ov[o] = (m5[o] > 1.0) ? 1.0f : 0.0f;
    float* op = out + ((size_t)t * BB + e) * 6;
    ((float2*)op)[0] = make_float2(ov[0], ov[1]);
    ((float2*)op)[1] = make_float2(ov[2], ov[3]);
    ((float2*)op)[2] = make_float2(ov[4], ov[5]);
  }
}

extern "C" void kernel_launch(void* const* d_in, const int* in_sizes, int n_in,
                              void* d_out, int out_size, void* d_ws, size_t ws_size,
                              hipStream_t stream) {
  const float* x  = (const float*)d_in[0];
  const float* W1 = (const float*)d_in[1];
  const float* W2 = (const float*)d_in[2];
  const float* W3 = (const float*)d_in[3];
  const float* W4 = (const float*)d_in[4];
  const float* W5 = (const float*)d_in[5];
  float* out = (float*)d_out;
  double* Wd = (double*)d_ws;

  prep_weights<<<17, 256, 0, stream>>>(W1, W2, W3, W4, W5, Wd);

  if (ws_size >= WS_NEEDED) {
    char* base = (char*)d_ws;
    uint32_t* mlo = (uint32_t*)(base + WS_MASK_BASE);
    uint32_t* mhi = (uint32_t*)(base + WS_MASK_BASE + WS_MASK_STRIDE);
    uint32_t* m2  = (uint32_t*)(base + WS_MASK_BASE + 2 * (size_t)WS_MASK_STRIDE);
    snn_l1<<<2048, 256, 0, stream>>>(x, Wd, mlo, mhi);
    snn_l2<<<1024, 256, 0, stream>>>(Wd, mlo, mhi, m2);
    snn_l345<<<1024, 256, 0, stream>>>(Wd, m2, out);
  } else {
    snn_f64<<<BB / 256, 256, 0, stream>>>(x, Wd, out);
  }
}